// Round 8
// baseline (79.860 us; speedup 1.0000x reference)
//
#include <hip/hip_runtime.h>
#include <hip/hip_bf16.h>
#include <math.h>

#define CC 512
#define HH 64
#define WW 96
#define NN 16
#define HW (HH*WW)        // 6144
#define NA 9
#define NLOC 36
#define NSC 18
#define NO_PAD 64         // 54 outputs padded to 64 (4 N-tiles of 16)

typedef __attribute__((ext_vector_type(4))) float f32x4;
typedef __attribute__((ext_vector_type(8))) short s16x8;
typedef __attribute__((ext_vector_type(2))) unsigned int u32x2;

__device__ __forceinline__ unsigned short f2bf(float f) {
    // compiler-friendly path -> v_cvt (RNE); m240: scalar casts are the good path
    __hip_bfloat16 h = __float2bfloat16(f);
    union { __hip_bfloat16 h; unsigned short u; } cv;
    cv.h = h;
    return cv.u;
}
__device__ __forceinline__ unsigned pk2(float lo, float hi) {
    return (unsigned)f2bf(lo) | ((unsigned)f2bf(hi) << 16);
}

// ---------------------------------------------------------------------------
// Kernel 1 (fused prep): blocks 0..127 convert weights to bf16 (padded to 64
// rows, wbf[o][c]); blocks 128..343 write the anchor grid (f64, matches numpy).
// ---------------------------------------------------------------------------
__global__ void prep_kernel(const float* __restrict__ lw,
                            const float* __restrict__ sw,
                            unsigned short* __restrict__ wbf,
                            float* __restrict__ out3) {
    int b = blockIdx.x;
    if (b < 128) {
        int i = b * 256 + threadIdx.x;        // over 64*512
        int o = i >> 9, c = i & 511;
        float v = 0.0f;
        if (o < NLOC) v = lw[o * CC + c];
        else if (o < 54) v = sw[(o - NLOC) * CC + c];
        wbf[i] = f2bf(v);
    } else {
        int t = (b - 128) * 256 + threadIdx.x;   // over HW*NA
        if (t >= HW * NA) return;
        int a   = t % NA;
        int rem = t / NA;
        int h = rem / WW, w = rem % WW;
        int ri = a / 3, si = a % 3;
        const double ratios[3] = {0.5, 1.0, 2.0};
        const double scales[3] = {8.0, 16.0, 32.0};
        double ha = 16.0 * scales[si] * sqrt(ratios[ri]);
        double wa = 16.0 * scales[si] * sqrt(1.0 / ratios[ri]);
        float y1 = (float)(8.0 - ha * 0.5);
        float x1 = (float)(8.0 - wa * 0.5);
        float y2 = (float)(8.0 + ha * 0.5);
        float x2 = (float)(8.0 + wa * 0.5);
        float sy = (float)(h * 16);
        float sx = (float)(w * 16);
        float4 v = make_float4(sy + y1, sx + x1, sy + y2, sx + x2);
        *reinterpret_cast<float4*>(out3 + (size_t)t * 4) = v;
    }
}

// ---------------------------------------------------------------------------
// Kernel 2: MFMA main, depth-3 pipeline. Block = 256 = 4 waves, 64 positions.
// Round t: issue chunk t+3 loads | ds_write chunk t+1 (in flight ~2 rounds ->
// HBM latency covered) | compute chunk t from buf[t%3]. Triple-buffered LDS
// (3 x 8KB). Raw s_barrier + lgkmcnt(0) only (prefetch loads stay in flight
// across barriers). x staged bf16, subtiled [c/4][p/16][c%4][p%16]:
// ds_write_b64 + ds_read_b64_tr_b16 both bank-balanced. B-frags: 16B loads,
// L1-hot, split per K-step to cap VGPR.
// ---------------------------------------------------------------------------
__launch_bounds__(256)
__global__ void rpn_mfma_kernel(const float* __restrict__ x,
                                const unsigned short* __restrict__ wbf,
                                const float* __restrict__ lb,
                                const float* __restrict__ sb,
                                float* __restrict__ out0,   // rpn_loc
                                float* __restrict__ out1,   // rpn_score
                                float* __restrict__ out2) { // rpn_fg_scores
    __shared__ unsigned short buf[3 * 4096];   // 24 KB

    const int tid  = threadIdx.x;
    const int lane = tid & 63;
    const int w    = tid >> 6;        // wave id = M-tile id
    const int col  = lane & 15;
    const int rgrp = lane >> 4;

    const int pbase = blockIdx.x * 64;          // 64 | HW -> single n per block
    const int n     = pbase / HW;
    const int rem   = pbase % HW;
    const float* xb = x + (size_t)n * CC * HW + rem;

    size_t goff[4];  int loff[4];
    #pragma unroll
    for (int i = 0; i < 4; ++i) {
        int q = i * 256 + tid, c = q >> 4, pq = q & 15;
        goff[i] = (size_t)c * HW + pq * 4;
        loff[i] = ((c >> 2) * 4 + (pq >> 2)) * 64 + (c & 3) * 16 + (pq & 3) * 4;
    }

    const unsigned lds0 = (unsigned)(uintptr_t)buf;
    const unsigned prec = 1024u * (unsigned)rgrp + 128u * (unsigned)w + 8u * (unsigned)col;

    f32x4 acc[4];
    #pragma unroll
    for (int nt = 0; nt < 4; ++nt) acc[nt] = (f32x4){0.f, 0.f, 0.f, 0.f};

    // ---- prologue: chunk0 -> buf[0]; chunks 1,2 in registers/in flight ----
    float4 c0[4], pW[4], pN[4];
    #pragma unroll
    for (int i = 0; i < 4; ++i)
        c0[i] = *reinterpret_cast<const float4*>(xb + goff[i]);                    // chunk 0
    #pragma unroll
    for (int i = 0; i < 4; ++i)
        pW[i] = *reinterpret_cast<const float4*>(xb + (size_t)64 * HW + goff[i]);  // chunk 1
    #pragma unroll
    for (int i = 0; i < 4; ++i)
        pN[i] = *reinterpret_cast<const float4*>(xb + (size_t)128 * HW + goff[i]); // chunk 2
    #pragma unroll
    for (int i = 0; i < 4; ++i) {
        u32x2 pk;
        pk.x = pk2(c0[i].x, c0[i].y);
        pk.y = pk2(c0[i].z, c0[i].w);
        *reinterpret_cast<u32x2*>(&buf[loff[i]]) = pk;
    }
    asm volatile("s_waitcnt lgkmcnt(0)" ::: "memory");
    __builtin_amdgcn_s_barrier();

    #pragma unroll 1
    for (int t = 0; t < 8; ++t) {
        const int cb = t * 64;
        // issue chunk t+3 loads (land ~2 rounds from now at ds_write time)
        float4 nx[4];
        if (t < 5) {
            #pragma unroll
            for (int i = 0; i < 4; ++i)
                nx[i] = *reinterpret_cast<const float4*>(
                    xb + (size_t)(cb + 192) * HW + goff[i]);
        }
        // ds_write chunk t+1 (loads issued at round t-2 -> latency covered)
        if (t < 7) {
            unsigned short* bw = &buf[((t + 1) % 3) * 4096];
            #pragma unroll
            for (int i = 0; i < 4; ++i) {
                u32x2 pk;
                pk.x = pk2(pW[i].x, pW[i].y);
                pk.y = pk2(pW[i].z, pW[i].w);
                *reinterpret_cast<u32x2*>(&bw[loff[i]]) = pk;
            }
        }
        // A fragments via hardware transpose-read from buf[t%3]
        unsigned ab = lds0 + (unsigned)((t % 3) * 8192) + prec;
        u32x2 a00, a01, a10, a11;
        asm volatile("ds_read_b64_tr_b16 %0, %1"             : "=v"(a00) : "v"(ab));
        asm volatile("ds_read_b64_tr_b16 %0, %1 offset:512"  : "=v"(a01) : "v"(ab));
        asm volatile("ds_read_b64_tr_b16 %0, %1 offset:4096" : "=v"(a10) : "v"(ab));
        asm volatile("ds_read_b64_tr_b16 %0, %1 offset:4608" : "=v"(a11) : "v"(ab));
        // B fragments, K-step 0 (16B contiguous, L1-hot)
        s16x8 b0[4];
        #pragma unroll
        for (int nt = 0; nt < 4; ++nt)
            b0[nt] = *reinterpret_cast<const s16x8*>(
                wbf + (size_t)(nt * 16 + col) * CC + cb + rgrp * 8);
        asm volatile("s_waitcnt lgkmcnt(0)" ::: "memory");
        __builtin_amdgcn_sched_barrier(0);   // rule #18

        union { u32x2 q[2]; s16x8 v; } fa0, fa1;
        fa0.q[0] = a00; fa0.q[1] = a01;
        fa1.q[0] = a10; fa1.q[1] = a11;

        #pragma unroll
        for (int nt = 0; nt < 4; ++nt)
            acc[nt] = __builtin_amdgcn_mfma_f32_16x16x32_bf16(fa0.v, b0[nt], acc[nt], 0, 0, 0);
        // B fragments, K-step 1 (issue overlaps K-step-0 MFMAs)
        s16x8 b1[4];
        #pragma unroll
        for (int nt = 0; nt < 4; ++nt)
            b1[nt] = *reinterpret_cast<const s16x8*>(
                wbf + (size_t)(nt * 16 + col) * CC + cb + 32 + rgrp * 8);
        #pragma unroll
        for (int nt = 0; nt < 4; ++nt)
            acc[nt] = __builtin_amdgcn_mfma_f32_16x16x32_bf16(fa1.v, b1[nt], acc[nt], 0, 0, 0);

        // rotate pending sets
        #pragma unroll
        for (int i = 0; i < 4; ++i) pW[i] = pN[i];
        if (t < 5) {
            #pragma unroll
            for (int i = 0; i < 4; ++i) pN[i] = nx[i];
        }
        asm volatile("s_waitcnt lgkmcnt(0)" ::: "memory");   // drain ds_writes
        __builtin_amdgcn_s_barrier();
    }

    // ---- epilogue: bias + stores + fg softmax (score pairs in lanes l, l^1) ----
    #pragma unroll
    for (int nt = 0; nt < 4; ++nt) {
        int o = nt * 16 + col;
        float bias = (o < NLOC) ? lb[o] : ((o < 54) ? sb[o - NLOC] : 0.0f);
        #pragma unroll
        for (int r = 0; r < 4; ++r) {
            float val  = acc[nt][r] + bias;
            float part = __shfl_xor(val, 1);
            int p = pbase + w * 16 + rgrp * 4 + r;
            if (o < NLOC) {
                out0[(size_t)p * NLOC + o] = val;
            } else if (o < 54) {
                int os = o - NLOC;
                out1[(size_t)p * NSC + os] = val;
                if ((os & 1) == 0)
                    out2[(size_t)p * NA + (os >> 1)] = 1.0f / (1.0f + __expf(val - part));
            }
        }
    }
}

extern "C" void kernel_launch(void* const* d_in, const int* in_sizes, int n_in,
                              void* d_out, int out_size, void* d_ws, size_t ws_size,
                              hipStream_t stream) {
    const float* x  = (const float*)d_in[0];
    const float* lw = (const float*)d_in[1];
    const float* lb = (const float*)d_in[2];
    const float* sw = (const float*)d_in[3];
    const float* sb = (const float*)d_in[4];

    float* out0 = (float*)d_out;                          // (16, 55296, 4)
    float* out1 = out0 + (size_t)NN * HW * NLOC;          // (16, 64, 96, 18)
    float* out2 = out1 + (size_t)NN * HW * NSC;           // (16, 55296)
    float* out3 = out2 + (size_t)NN * HW * NA;            // (55296, 4)

    unsigned short* wbf = (unsigned short*)d_ws;          // 64*512*2 = 64 KB

    prep_kernel<<<344, 256, 0, stream>>>(lw, sw, wbf, out3);

    int grid_m = NN * HW / 64;                            // 1536
    rpn_mfma_kernel<<<grid_m, 256, 0, stream>>>(x, wbf, lb, sb, out0, out1, out2);
}

// Round 9
// 67.409 us; speedup vs baseline: 1.1847x; 1.1847x over previous
//
#include <hip/hip_runtime.h>
#include <hip/hip_bf16.h>
#include <math.h>

#define CC 512
#define HH 64
#define WW 96
#define NN 16
#define HW (HH*WW)        // 6144
#define NA 9
#define NLOC 36
#define NSC 18
#define NO_PAD 64         // 54 outputs padded to 64 (4 N-tiles of 16)

typedef __attribute__((ext_vector_type(4))) float f32x4;
typedef __attribute__((ext_vector_type(8))) short s16x8;

__device__ __forceinline__ unsigned short f2bf(float f) {
    __hip_bfloat16 h = __float2bfloat16(f);
    union { __hip_bfloat16 h; unsigned short u; } cv;
    cv.h = h;
    return cv.u;
}
__device__ __forceinline__ unsigned pk2(float lo, float hi) {
    return (unsigned)f2bf(lo) | ((unsigned)f2bf(hi) << 16);
}

// ---------------------------------------------------------------------------
// Kernel 1 (fused prep): blocks 0..127 convert weights to bf16 (padded to 64
// rows, wbf[o][c]); blocks 128..343 write the anchor grid (f64, matches numpy).
// ---------------------------------------------------------------------------
__global__ void prep_kernel(const float* __restrict__ lw,
                            const float* __restrict__ sw,
                            unsigned short* __restrict__ wbf,
                            float* __restrict__ out3) {
    int b = blockIdx.x;
    if (b < 128) {
        int i = b * 256 + threadIdx.x;        // over 64*512
        int o = i >> 9, c = i & 511;
        float v = 0.0f;
        if (o < NLOC) v = lw[o * CC + c];
        else if (o < 54) v = sw[(o - NLOC) * CC + c];
        wbf[i] = f2bf(v);
    } else {
        int t = (b - 128) * 256 + threadIdx.x;   // over HW*NA
        if (t >= HW * NA) return;
        int a   = t % NA;
        int rem = t / NA;
        int h = rem / WW, w = rem % WW;
        int ri = a / 3, si = a % 3;
        const double ratios[3] = {0.5, 1.0, 2.0};
        const double scales[3] = {8.0, 16.0, 32.0};
        double ha = 16.0 * scales[si] * sqrt(ratios[ri]);
        double wa = 16.0 * scales[si] * sqrt(1.0 / ratios[ri]);
        float y1 = (float)(8.0 - ha * 0.5);
        float x1 = (float)(8.0 - wa * 0.5);
        float y2 = (float)(8.0 + ha * 0.5);
        float x2 = (float)(8.0 + wa * 0.5);
        float sy = (float)(h * 16);
        float sx = (float)(w * 16);
        float4 v = make_float4(sy + y1, sx + x1, sy + y2, sx + x2);
        *reinterpret_cast<float4*>(out3 + (size_t)t * 4) = v;
    }
}

// ---------------------------------------------------------------------------
// Kernel 2: barrier-free MFMA GEMM. No LDS. Block = 256 = 4 independent
// waves; wave w owns the 16-pos M-tile [pbase + w*16, +16).
// A-fragment loaded DIRECTLY from global: lane needs x[k0+j][pos], j=0..7
// (dword loads; each instr coalesces as 4 x 64B segments -> same bytes/instr
// as the staged path, zero LDS/barrier overhead). Depth-2 register prefetch;
// waves free-run, 24 unsynced waves/CU hide remaining latency.
// A layout: row = lane&15 (position), k = (lane>>4)*8 + j.
// B layout: col = lane&15 (output o), k = (lane>>4)*8 + j (16B contiguous,
// L2-hot). C/D: col = lane&15 (o), row = (lane>>4)*4 + reg (position).
// ---------------------------------------------------------------------------
__launch_bounds__(256, 6)
__global__ void rpn_mfma_kernel(const float* __restrict__ x,
                                const unsigned short* __restrict__ wbf,
                                const float* __restrict__ lb,
                                const float* __restrict__ sb,
                                float* __restrict__ out0,   // rpn_loc
                                float* __restrict__ out1,   // rpn_score
                                float* __restrict__ out2) { // rpn_fg_scores
    const int tid  = threadIdx.x;
    const int lane = tid & 63;
    const int w    = tid >> 6;        // wave id = M-tile id
    const int col  = lane & 15;
    const int rgrp = lane >> 4;
    const int krow = rgrp * 8;        // lane's channel slice within a K-step

    const int pbase = blockIdx.x * 64;          // 64 | HW -> single n per block
    const int n     = pbase / HW;
    const int rem   = pbase % HW;
    // lane's position column in x
    const float* xA = x + (size_t)n * CC * HW + rem + w * 16 + col;

    f32x4 acc[4];
    #pragma unroll
    for (int nt = 0; nt < 4; ++nt) acc[nt] = (f32x4){0.f, 0.f, 0.f, 0.f};

    float a[8], an[8];
    #pragma unroll
    for (int j = 0; j < 8; ++j)
        a[j] = xA[(size_t)(krow + j) * HW];          // K-step 0

    #pragma unroll 1
    for (int ks = 0; ks < 16; ++ks) {
        const int k0 = ks * 32 + krow;
        // prefetch next K-step's A slice (stays in flight through the MFMAs)
        if (ks < 15) {
            #pragma unroll
            for (int j = 0; j < 8; ++j)
                an[j] = xA[(size_t)(k0 + 32 + j) * HW];
        }
        // B fragments: 16B contiguous, L2-hot
        s16x8 bfr[4];
        #pragma unroll
        for (int nt = 0; nt < 4; ++nt)
            bfr[nt] = *reinterpret_cast<const s16x8*>(
                wbf + (size_t)(nt * 16 + col) * CC + k0);
        // pack A to bf16 fragment
        union { unsigned u[4]; s16x8 v; } fa;
        #pragma unroll
        for (int j = 0; j < 4; ++j) fa.u[j] = pk2(a[2 * j], a[2 * j + 1]);

        #pragma unroll
        for (int nt = 0; nt < 4; ++nt)
            acc[nt] = __builtin_amdgcn_mfma_f32_16x16x32_bf16(fa.v, bfr[nt], acc[nt], 0, 0, 0);

        #pragma unroll
        for (int j = 0; j < 8; ++j) a[j] = an[j];
    }

    // ---- epilogue: bias + stores + fg softmax (score pairs in lanes l, l^1) ----
    #pragma unroll
    for (int nt = 0; nt < 4; ++nt) {
        int o = nt * 16 + col;
        float bias = (o < NLOC) ? lb[o] : ((o < 54) ? sb[o - NLOC] : 0.0f);
        #pragma unroll
        for (int r = 0; r < 4; ++r) {
            float val  = acc[nt][r] + bias;
            float part = __shfl_xor(val, 1);
            int p = pbase + w * 16 + rgrp * 4 + r;
            if (o < NLOC) {
                out0[(size_t)p * NLOC + o] = val;
            } else if (o < 54) {
                int os = o - NLOC;
                out1[(size_t)p * NSC + os] = val;
                if ((os & 1) == 0)
                    out2[(size_t)p * NA + (os >> 1)] = 1.0f / (1.0f + __expf(val - part));
            }
        }
    }
}

extern "C" void kernel_launch(void* const* d_in, const int* in_sizes, int n_in,
                              void* d_out, int out_size, void* d_ws, size_t ws_size,
                              hipStream_t stream) {
    const float* x  = (const float*)d_in[0];
    const float* lw = (const float*)d_in[1];
    const float* lb = (const float*)d_in[2];
    const float* sw = (const float*)d_in[3];
    const float* sb = (const float*)d_in[4];

    float* out0 = (float*)d_out;                          // (16, 55296, 4)
    float* out1 = out0 + (size_t)NN * HW * NLOC;          // (16, 64, 96, 18)
    float* out2 = out1 + (size_t)NN * HW * NSC;           // (16, 55296)
    float* out3 = out2 + (size_t)NN * HW * NA;            // (55296, 4)

    unsigned short* wbf = (unsigned short*)d_ws;          // 64*512*2 = 64 KB

    prep_kernel<<<344, 256, 0, stream>>>(lw, sw, wbf, out3);

    int grid_m = NN * HW / 64;                            // 1536
    rpn_mfma_kernel<<<grid_m, 256, 0, stream>>>(x, wbf, lb, sb, out0, out1, out2);
}

// Round 10
// 51.937 us; speedup vs baseline: 1.5377x; 1.2979x over previous
//
#include <hip/hip_runtime.h>
#include <hip/hip_bf16.h>
#include <math.h>

#define CC 512
#define HH 64
#define WW 96
#define NN 16
#define HW (HH*WW)        // 6144
#define NA 9
#define NLOC 36
#define NSC 18
#define NO_PAD 64         // 54 outputs padded to 64 (4 N-tiles of 16)

typedef __attribute__((ext_vector_type(4))) float f32x4;
typedef __attribute__((ext_vector_type(8))) short s16x8;

__device__ __forceinline__ unsigned short f2bf(float f) {
    __hip_bfloat16 h = __float2bfloat16(f);
    union { __hip_bfloat16 h; unsigned short u; } cv;
    cv.h = h;
    return cv.u;
}
__device__ __forceinline__ unsigned pk2(float lo, float hi) {
    return (unsigned)f2bf(lo) | ((unsigned)f2bf(hi) << 16);
}

// ---------------------------------------------------------------------------
// Kernel 1 (fused prep): blocks 0..127 convert weights to bf16 (padded to 64
// rows, wbf[o][c]); blocks 128..343 write the anchor grid (f64, matches numpy).
// ---------------------------------------------------------------------------
__global__ void prep_kernel(const float* __restrict__ lw,
                            const float* __restrict__ sw,
                            unsigned short* __restrict__ wbf,
                            float* __restrict__ out3) {
    int b = blockIdx.x;
    if (b < 128) {
        int i = b * 256 + threadIdx.x;        // over 64*512
        int o = i >> 9, c = i & 511;
        float v = 0.0f;
        if (o < NLOC) v = lw[o * CC + c];
        else if (o < 54) v = sw[(o - NLOC) * CC + c];
        wbf[i] = f2bf(v);
    } else {
        int t = (b - 128) * 256 + threadIdx.x;   // over HW*NA
        if (t >= HW * NA) return;
        int a   = t % NA;
        int rem = t / NA;
        int h = rem / WW, w = rem % WW;
        int ri = a / 3, si = a % 3;
        const double ratios[3] = {0.5, 1.0, 2.0};
        const double scales[3] = {8.0, 16.0, 32.0};
        double ha = 16.0 * scales[si] * sqrt(ratios[ri]);
        double wa = 16.0 * scales[si] * sqrt(1.0 / ratios[ri]);
        float y1 = (float)(8.0 - ha * 0.5);
        float x1 = (float)(8.0 - wa * 0.5);
        float y2 = (float)(8.0 + ha * 0.5);
        float x2 = (float)(8.0 + wa * 0.5);
        float sy = (float)(h * 16);
        float sx = (float)(w * 16);
        float4 v = make_float4(sy + y1, sx + x1, sy + y2, sx + x2);
        *reinterpret_cast<float4*>(out3 + (size_t)t * 4) = v;
    }
}

// ---------------------------------------------------------------------------
// Kernel 2: barrier-free MFMA GEMM, M_rep=2. No LDS. Block = 4 independent
// waves over 128 consecutive positions; wave w owns M-tiles w and w+4
// (positions pbase+w*16 and pbase+w*16+64). Per K-step: 16 independent A
// dword-loads (2 tiles x 8) + 4 B 16B-loads feeding 8 MFMAs; B amortized 2x.
// __launch_bounds__(256,3) -> 168-VGPR budget so the ping-pong prefetch
// SURVIVES regalloc (r9 failed at 28 VGPR = serialized loads).
// Grid = 768 = exactly 3 blocks/CU; bijective XCD swizzle (768%8==0) gives
// each XCD a contiguous ~25MB slab of x -> L2/HBM locality.
// A layout: row = lane&15 (position), k = (lane>>4)*8 + j.
// B layout: col = lane&15 (output o). C/D: col = o, row = (lane>>4)*4 + reg.
// ---------------------------------------------------------------------------
__launch_bounds__(256, 3)
__global__ void rpn_mfma_kernel(const float* __restrict__ x,
                                const unsigned short* __restrict__ wbf,
                                const float* __restrict__ lb,
                                const float* __restrict__ sb,
                                float* __restrict__ out0,   // rpn_loc
                                float* __restrict__ out1,   // rpn_score
                                float* __restrict__ out2) { // rpn_fg_scores
    const int tid  = threadIdx.x;
    const int lane = tid & 63;
    const int w    = tid >> 6;        // wave id
    const int col  = lane & 15;
    const int rgrp = lane >> 4;
    const int krow = rgrp * 8;        // lane's channel slice within a K-step

    // XCD-aware bijective swizzle: 768 blocks, 8 XCDs, 96 contiguous each
    const int bid  = blockIdx.x;
    const int swz  = (bid & 7) * 96 + (bid >> 3);
    const int pbase = swz * 128;                // 128 | HW -> single n per block
    const int n     = pbase / HW;
    const int rem   = pbase % HW;
    const float* xA0 = x + (size_t)n * CC * HW + rem + w * 16 + col;  // tile m=0
    const float* xA1 = xA0 + 64;                                      // tile m=1

    f32x4 acc0[4], acc1[4];
    #pragma unroll
    for (int nt = 0; nt < 4; ++nt) {
        acc0[nt] = (f32x4){0.f, 0.f, 0.f, 0.f};
        acc1[nt] = (f32x4){0.f, 0.f, 0.f, 0.f};
    }

    float a0[8], a1[8], p0[8], p1[8];
    #pragma unroll
    for (int j = 0; j < 8; ++j) {
        a0[j] = xA0[(size_t)(krow + j) * HW];          // K-step 0
        a1[j] = xA1[(size_t)(krow + j) * HW];
    }

    #pragma unroll 2
    for (int ks = 0; ks < 16; ++ks) {
        const int kb = ks * 32;
        // prefetch next K-step's A slices (16 independent loads in flight)
        if (ks < 15) {
            #pragma unroll
            for (int j = 0; j < 8; ++j) {
                p0[j] = xA0[(size_t)(kb + 32 + krow + j) * HW];
                p1[j] = xA1[(size_t)(kb + 32 + krow + j) * HW];
            }
        }
        // B fragments: 16B contiguous, L1/L2-hot, shared by both M-tiles
        s16x8 bfr[4];
        #pragma unroll
        for (int nt = 0; nt < 4; ++nt)
            bfr[nt] = *reinterpret_cast<const s16x8*>(
                wbf + (size_t)(nt * 16 + col) * CC + kb + krow);
        // pack A to bf16 fragments
        union { unsigned u[4]; s16x8 v; } fa0, fa1;
        #pragma unroll
        for (int j = 0; j < 4; ++j) {
            fa0.u[j] = pk2(a0[2 * j], a0[2 * j + 1]);
            fa1.u[j] = pk2(a1[2 * j], a1[2 * j + 1]);
        }

        #pragma unroll
        for (int nt = 0; nt < 4; ++nt)
            acc0[nt] = __builtin_amdgcn_mfma_f32_16x16x32_bf16(fa0.v, bfr[nt], acc0[nt], 0, 0, 0);
        #pragma unroll
        for (int nt = 0; nt < 4; ++nt)
            acc1[nt] = __builtin_amdgcn_mfma_f32_16x16x32_bf16(fa1.v, bfr[nt], acc1[nt], 0, 0, 0);

        #pragma unroll
        for (int j = 0; j < 8; ++j) { a0[j] = p0[j]; a1[j] = p1[j]; }
    }

    // ---- epilogue: bias + stores + fg softmax (score pairs in lanes l, l^1) ----
    #pragma unroll
    for (int m = 0; m < 2; ++m) {
        #pragma unroll
        for (int nt = 0; nt < 4; ++nt) {
            int o = nt * 16 + col;
            float bias = (o < NLOC) ? lb[o] : ((o < 54) ? sb[o - NLOC] : 0.0f);
            #pragma unroll
            for (int r = 0; r < 4; ++r) {
                float val  = (m == 0 ? acc0[nt][r] : acc1[nt][r]) + bias;
                float part = __shfl_xor(val, 1);
                int p = pbase + w * 16 + m * 64 + rgrp * 4 + r;
                if (o < NLOC) {
                    out0[(size_t)p * NLOC + o] = val;
                } else if (o < 54) {
                    int os = o - NLOC;
                    out1[(size_t)p * NSC + os] = val;
                    if ((os & 1) == 0)
                        out2[(size_t)p * NA + (os >> 1)] = 1.0f / (1.0f + __expf(val - part));
                }
            }
        }
    }
}

extern "C" void kernel_launch(void* const* d_in, const int* in_sizes, int n_in,
                              void* d_out, int out_size, void* d_ws, size_t ws_size,
                              hipStream_t stream) {
    const float* x  = (const float*)d_in[0];
    const float* lw = (const float*)d_in[1];
    const float* lb = (const float*)d_in[2];
    const float* sw = (const float*)d_in[3];
    const float* sb = (const float*)d_in[4];

    float* out0 = (float*)d_out;                          // (16, 55296, 4)
    float* out1 = out0 + (size_t)NN * HW * NLOC;          // (16, 64, 96, 18)
    float* out2 = out1 + (size_t)NN * HW * NSC;           // (16, 55296)
    float* out3 = out2 + (size_t)NN * HW * NA;            // (55296, 4)

    unsigned short* wbf = (unsigned short*)d_ws;          // 64*512*2 = 64 KB

    prep_kernel<<<344, 256, 0, stream>>>(lw, sw, wbf, out3);

    int grid_m = NN * HW / 128;                           // 768
    rpn_mfma_kernel<<<grid_m, 256, 0, stream>>>(x, wbf, lb, sb, out0, out1, out2);
}